// Round 5
// baseline (182.015 us; speedup 1.0000x reference)
//
#include <hip/hip_runtime.h>

typedef float nf4 __attribute__((ext_vector_type(4)));

// Cell2Tissue: conv3x3(cell) -> avgpool4 -> add into per-sample ROI of tissue -> broadcast x4.
//
// Fused pipeline (3 kernels):
//  k_gemm  : per (pooled-row i, split): stage 6 cell rows -> vertical 4-sums (regs) ->
//            box row-triple in LDS -> FMA vs per-block-transposed w slice.
//            part[s][c][i*64+j] = sum_{ci in split s} sum_k w[c][ci][k]*box[ci][4i+dy][4j+dx]
//  k_avgfin: avg = bias + (sum_s part[s]) / 16
//  k_out   : out[b][j][c][h][w] = tissue[j][c][h][w] + (in ROI_j ? avg[...] : 0), b=0..3
//
// ws layout (bytes): part @0 (33,554,432 = 16 splits x 2 MB) | avg @33,554,432 (2,097,152)

#define NSPLIT 16
#define CIPS   8          // input channels per split

__global__ __launch_bounds__(256) void k_gemm(const float* __restrict__ cell,
                                              const float* __restrict__ w,
                                              float* __restrict__ part) {
    __shared__ float vs[3][260];   // vertical 4-sums; index = cell col + 1 (cols -1..257)
    __shared__ float bx[3][256];   // box rows yy = 4i+dy
    __shared__ float wl[1152];     // wl[k*128 + c] = w[c][ci][k]
    int i     = blockIdx.x;        // pooled row 0..63
    int split = blockIdx.y;        // 0..15
    int tid = threadIdx.x;
    int cg  = tid & 31;            // out-channel group: c = 4*cg + a
    int pg  = tid >> 5;            // position group: j = 8*pg + p

    // zero halo columns of vs once (never overwritten: threads write vs[dy][1..256])
    if (tid < 9) {
        int dy = tid / 3, q = tid % 3;
        vs[dy][q == 0 ? 0 : 256 + q] = 0.f;   // slots 0, 257, 258
    }

    float acc[4][8];
#pragma unroll
    for (int a = 0; a < 4; ++a)
#pragma unroll
        for (int p = 0; p < 8; ++p) acc[a][p] = 0.f;

    int r0 = 4 * i - 1;
    for (int t = 0; t < CIPS; ++t) {
        int ci = split * CIPS + t;
        // --- load 6 cell rows (col = tid), zero OOB rows; coalesced per row ---
        const float* base = cell + (size_t)ci * 65536;
        float cr[6];
#pragma unroll
        for (int r = 0; r < 6; ++r) {
            int row = r0 + r;
            cr[r] = ((unsigned)row < 256u) ? base[row * 256 + tid] : 0.f;
        }
        __syncthreads();                       // prior iter done reading wl / vs
        vs[0][tid + 1] = cr[0] + cr[1] + cr[2] + cr[3];
        vs[1][tid + 1] = cr[1] + cr[2] + cr[3] + cr[4];
        vs[2][tid + 1] = cr[2] + cr[3] + cr[4] + cr[5];
        // --- stage transposed w slice: wl[k*128+c] = w[c*1152 + ci*9 + k] ---
#pragma unroll
        for (int s = 0; s < 5; ++s) {
            int q = tid + 256 * s;
            if (q < 1152)
                wl[q] = w[(size_t)(q & 127) * 1152 + (size_t)ci * 9 + (q >> 7)];
        }
        __syncthreads();                       // vs + wl visible
        // --- box: bx[dy][xx] = vs[dy][xx] + .. + vs[dy][xx+3]  (cell cols xx-1..xx+2) ---
#pragma unroll
        for (int dy = 0; dy < 3; ++dy)
            bx[dy][tid] = vs[dy][tid] + vs[dy][tid + 1] + vs[dy][tid + 2] + vs[dy][tid + 3];
        __syncthreads();                       // bx visible
        // --- FMA ---
        nf4 wv[9];
#pragma unroll
        for (int k = 0; k < 9; ++k)
            wv[k] = *(const nf4*)&wl[k * 128 + 4 * cg];
#pragma unroll
        for (int p = 0; p < 8; ++p) {
            int j = 8 * pg + p;
            nf4 b0 = *(const nf4*)&bx[0][4 * j];
            nf4 b1 = *(const nf4*)&bx[1][4 * j];
            nf4 b2 = *(const nf4*)&bx[2][4 * j];
#pragma unroll
            for (int a = 0; a < 4; ++a) {
                float sm = acc[a][p];
                sm = fmaf(wv[0][a], b0[0], sm);
                sm = fmaf(wv[1][a], b0[1], sm);
                sm = fmaf(wv[2][a], b0[2], sm);
                sm = fmaf(wv[3][a], b1[0], sm);
                sm = fmaf(wv[4][a], b1[1], sm);
                sm = fmaf(wv[5][a], b1[2], sm);
                sm = fmaf(wv[6][a], b2[0], sm);
                sm = fmaf(wv[7][a], b2[1], sm);
                sm = fmaf(wv[8][a], b2[2], sm);
                acc[a][p] = sm;
            }
        }
    }

    float* dst = part + (size_t)split * 524288;
#pragma unroll
    for (int a = 0; a < 4; ++a) {
        int c = 4 * cg + a;
        float* row = dst + (size_t)c * 4096 + i * 64 + 8 * pg;
        float4 lo = make_float4(acc[a][0], acc[a][1], acc[a][2], acc[a][3]);
        float4 hi = make_float4(acc[a][4], acc[a][5], acc[a][6], acc[a][7]);
        *(float4*)(row)     = lo;
        *(float4*)(row + 4) = hi;
    }
}

__global__ __launch_bounds__(256) void k_avgfin(const float* __restrict__ part,
                                                const float* __restrict__ bias,
                                                float* __restrict__ avg) {
    int idx4 = blockIdx.x * 256 + threadIdx.x;         // < 131072 float4s
    int c = idx4 >> 10;
    nf4 s = {0.f, 0.f, 0.f, 0.f};
#pragma unroll
    for (int sp = 0; sp < NSPLIT; ++sp)
        s += *(const nf4*)(part + (size_t)sp * 524288 + (size_t)idx4 * 4);
    nf4 o = s * 0.0625f + bias[c];
    *(nf4*)(avg + (size_t)idx4 * 4) = o;
}

__global__ __launch_bounds__(256) void k_out(const float* __restrict__ tissue,
                                             const float* __restrict__ avg,
                                             const int* __restrict__ loc,
                                             float* __restrict__ out) {
    int bid = blockIdx.x, tid = threadIdx.x;
    int j = bid >> 13;                                 // sample (block-uniform -> s_load loc)
    int c = (bid >> 6) & 127;
    int h = ((bid << 2) | (tid >> 6)) & 255;           // wave-uniform
    int w0 = (tid & 63) << 2;
    size_t f = ((size_t)bid << 10) | (unsigned)(tid << 2);

    nf4 v = __builtin_nontemporal_load((const nf4*)(tissue + f));

    // axis-1 (h) uses loc[:,1]; axis-2 (w) uses loc[:,0]; start = loc/4 - 32
    int sh = (loc[2 * j + 1] >> 2) - 32;
    int sw = (loc[2 * j]     >> 2) - 32;
    int ah = h - sh;
    if ((unsigned)ah < 64u) {
        const float* ar = avg + c * 4096 + ah * 64;
        int aw = w0 - sw;
        if (aw     >= 0 && aw     < 64) v[0] += ar[aw];
        if (aw + 1 >= 0 && aw + 1 < 64) v[1] += ar[aw + 1];
        if (aw + 2 >= 0 && aw + 2 < 64) v[2] += ar[aw + 2];
        if (aw + 3 >= 0 && aw + 3 < 64) v[3] += ar[aw + 3];
    }
#pragma unroll
    for (int b = 0; b < 4; ++b)
        __builtin_nontemporal_store(v, (nf4*)(out + (size_t)b * 33554432 + f));
}

extern "C" void kernel_launch(void* const* d_in, const int* in_sizes, int n_in,
                              void* d_out, int out_size, void* d_ws, size_t ws_size,
                              hipStream_t stream) {
    const float* tissue = (const float*)d_in[0];
    const float* cell   = (const float*)d_in[1];
    const int*   loc    = (const int*)d_in[2];
    const float* w      = (const float*)d_in[3];
    const float* bias   = (const float*)d_in[4];
    float* out = (float*)d_out;

    char* wsb = (char*)d_ws;
    float* part = (float*)(wsb);
    float* avg  = (float*)(wsb + 33554432);

    k_gemm<<<dim3(64, NSPLIT), 256, 0, stream>>>(cell, w, part);
    k_avgfin<<<512, 256, 0, stream>>>(part, bias, avg);
    k_out<<<32768, 256, 0, stream>>>(tissue, avg, loc, out);
}